// Round 3
// baseline (179.405 us; speedup 1.0000x reference)
//
#include <hip/hip_runtime.h>
#include <hip/hip_bf16.h>
#include <stdint.h>

// ---------------------------------------------------------------------------
// Decoder_10110353014984: LIF multistep (T=4) + linear head
//   x: [4,64,196,512] f32, W: [1000,512] f32, b: [1000] f32
//   y: [4,64,196,1000] f32
// R3: GEMM with swapped MFMA operands (A=W, B=S) so each lane holds 4
//     consecutive output cols -> float4 stores (16/thread, was 128 scalar).
//     Depth-2 counted-vmcnt pipeline: BM=128, BN=256, BK=64, 3 LDS buffers
//     (144KB), persistent 224 blocks x 7 jobs, batches issued 2 tiles ahead,
//     tile-top waits vmcnt(6)/(16) -- no full drains in the main loop.
// ---------------------------------------------------------------------------

typedef __attribute__((ext_vector_type(8))) short bf16x8;
typedef __attribute__((ext_vector_type(4))) float f32x4;

#define AS1(p) ((const __attribute__((address_space(1))) void*)(p))
#define AS3(p) ((__attribute__((address_space(3))) void*)(p))

static constexpr int     T_STEPS = 4;
static constexpr int64_t ESP     = 6422528;   // B*N*D = 64*196*512
static constexpr int     K_DIM   = 512;
static constexpr int     C_DIM   = 1000;
static constexpr int64_t M_ROWS  = 50176;     // T*B*N

__device__ __forceinline__ unsigned short f2bf(float f) {
  unsigned int u = __float_as_uint(f);
  u += 0x7FFFu + ((u >> 16) & 1u);            // round-to-nearest-even
  return (unsigned short)(u >> 16);
}

// ---------------------------------------------------------------------------
// Kernel 1: LIF dynamics -> bf16 spikes. Bit-exact vs reference:
// v += (x - v) * 0.5f (exact *0.5), spike iff v >= 1.0f, hard reset.
// ---------------------------------------------------------------------------
__global__ void lif_kernel(const float* __restrict__ x,
                           unsigned short* __restrict__ S) {
  const int64_t stride = (int64_t)gridDim.x * blockDim.x;
  const int64_t nquads = ESP / 4;
  for (int64_t q = (int64_t)blockIdx.x * blockDim.x + threadIdx.x;
       q < nquads; q += stride) {
    const int64_t s0 = q << 2;
    float v[4] = {0.f, 0.f, 0.f, 0.f};
#pragma unroll
    for (int t = 0; t < T_STEPS; ++t) {
      const float4 xt = *(const float4*)(x + (int64_t)t * ESP + s0);
      const float xa[4] = {xt.x, xt.y, xt.z, xt.w};
      ushort4 sp;
      unsigned short* spp = &sp.x;
#pragma unroll
      for (int j = 0; j < 4; ++j) {
        v[j] = v[j] + (xa[j] - v[j]) * 0.5f;   // charge
        const bool fire = (v[j] >= 1.0f);
        spp[j] = fire ? (unsigned short)0x3F80 : (unsigned short)0; // bf16 1/0
        if (fire) v[j] = 0.0f;                 // hard reset
      }
      *(ushort4*)(S + (int64_t)t * ESP + s0) = sp;
    }
  }
}

// ---------------------------------------------------------------------------
// Kernel 2: W f32[1000,512] -> bf16[1024,512], rows 1000..1023 zeroed.
// ---------------------------------------------------------------------------
__global__ void wconv_kernel(const float* __restrict__ W,
                             unsigned short* __restrict__ Wb) {
  const int idx = blockIdx.x * blockDim.x + threadIdx.x;  // 0..131071
  const int64_t base = (int64_t)idx * 4;
  const int row = (int)(base >> 9);
  ushort4 o;
  if (row < C_DIM) {
    const float4 wv = *(const float4*)(W + base);
    o.x = f2bf(wv.x); o.y = f2bf(wv.y); o.z = f2bf(wv.z); o.w = f2bf(wv.w);
  } else {
    o.x = o.y = o.z = o.w = 0;
  }
  *(ushort4*)(Wb + base) = o;
}

// ---------------------------------------------------------------------------
// Kernel 3: GEMM  Y[m,c] = sum_d S[m,d] * Wb[c,d] + b[c]
//
// Geometry: per job: M-tile 128 rows x N-tile 256 cols, BK=64, 8 K-tiles.
// 8 waves as (wc 0..3 c-groups of 64) x (wm 0..1 m-groups of 64).
// MFMA operands swapped: a=Wfrag (rows=c), b=Sfrag (rows=m) so D gives
// lane: m = lane&15, c-quad = (lane>>4)*4 + reg -> float4 stores.
//
// Pipeline: 3 LDS buffers, batch t (6 gload_lds: 4 W + 2 S) issued during
// tile t-2 into buf[t%3]. Tile-top: s_waitcnt vmcnt(N) + s_barrier, where
// N counts ops younger than the awaited batch:
//   steady: t0=16 (the 16 stores), t1..t6=6, t7=0 (batch7 is 2 tiles old).
// Cross-job: batch0' issued during t7 (before stores), job0 primed in
// prologue. Per-phase lgkmcnt(0) before MFMA guarantees ds_reads complete
// before the wave leaves the tile (required for buffer-reuse safety).
// ---------------------------------------------------------------------------
__global__ __launch_bounds__(512) void gemm_kernel(
    const unsigned short* __restrict__ S,
    const unsigned short* __restrict__ Wb,
    const float* __restrict__ bias,
    float* __restrict__ Y,
    float* __restrict__ dump) {
  __shared__ __attribute__((aligned(16))) unsigned short Ws3[3][256 * 64];
  __shared__ __attribute__((aligned(16))) unsigned short Ss3[3][128 * 64];

  const int tid  = threadIdx.x;
  const int lane = tid & 63;
  const int wid  = tid >> 6;          // 0..7
  const int wcb  = (wid >> 1) * 64;   // c-group base in [0,256)
  const int wmb  = (wid & 1) * 64;    // m-group base in [0,128)
  const int lr   = lane & 15;
  const int lkb  = (lane >> 4) * 16;

  // persistent job map: 224 blocks = 8 XCDs x 28; idx -> (cpart, ms);
  // job i (0..6): m_tile = 7*xcd + ms + 56*i  (bijective over 392 m-tiles),
  // so XCD k runs the 4 c-siblings of m-tiles {7k..7k+6} -> S L2-shared.
  const int bid   = blockIdx.x;
  const int xcd   = bid & 7;
  const int idx   = bid >> 3;         // 0..27
  const int cpart = idx & 3;
  const int ms    = idx >> 2;         // 0..6
  const int c0    = cpart * 256;
  const int mtb   = 7 * xcd + ms;

  const int srow = lane >> 3;                 // 0..7
  const int skb  = ((lane & 7) ^ srow) << 4;  // pre-swizzled global col

  const char* Sg  = (const char*)S;
  const char* Wg  = (const char*)Wb;
  char*       wsb = (char*)&Ws3[0][0];
  char*       ssb = (char*)&Ss3[0][0];

  auto stW = [&](int b, int k0, int iw) {
    const int64_t gr = c0 + iw * 64 + wid * 8 + srow;
    __builtin_amdgcn_global_load_lds(
        AS1(Wg + (gr * K_DIM + k0) * 2 + skb),
        AS3(wsb + b * 32768 + (iw * 64 + wid * 8) * 128), 16, 0, 0);
  };
  auto stS = [&](int b, int k0, int is, int64_t mr) {
    const int64_t gr = mr + is * 64 + wid * 8 + srow;
    __builtin_amdgcn_global_load_lds(
        AS1(Sg + (gr * K_DIM + k0) * 2 + skb),
        AS3(ssb + b * 16384 + (is * 64 + wid * 8) * 128), 16, 0, 0);
  };

  // bias per c-quad, fixed for all jobs (c0 constant per block)
  float4 bv[4];
#pragma unroll
  for (int ci = 0; ci < 4; ++ci) {
    const int cq = c0 + wcb + ci * 16 + (lane >> 4) * 4;
    if (cq < C_DIM) bv[ci] = *(const float4*)(bias + cq);
    else            bv[ci] = make_float4(0.f, 0.f, 0.f, 0.f);
  }

  f32x4 acc[4][4] = {};

#define PHASE(BUF, KBH, ...)                                                 \
  {                                                                          \
    const int   kb = (KBH) + lkb;                                            \
    const char* wp = wsb + (BUF) * 32768;                                    \
    const char* sp = ssb + (BUF) * 16384;                                    \
    bf16x8 wf[4], sf[4];                                                     \
    _Pragma("unroll")                                                        \
    for (int ci = 0; ci < 4; ++ci) {                                         \
      const int r = wcb + ci * 16 + lr;                                      \
      wf[ci] = *(const bf16x8*)(wp + r * 128 + (kb ^ ((r & 7) << 4)));       \
    }                                                                        \
    _Pragma("unroll")                                                        \
    for (int mj = 0; mj < 4; ++mj) {                                         \
      const int r = wmb + mj * 16 + lr;                                      \
      sf[mj] = *(const bf16x8*)(sp + r * 128 + (kb ^ ((r & 7) << 4)));       \
    }                                                                        \
    __VA_ARGS__;                                                             \
    __builtin_amdgcn_s_barrier();                                            \
    asm volatile("s_waitcnt lgkmcnt(0)" ::: "memory");                       \
    __builtin_amdgcn_sched_barrier(0);                                       \
    __builtin_amdgcn_s_setprio(1);                                           \
    _Pragma("unroll")                                                        \
    for (int ci = 0; ci < 4; ++ci)                                           \
      _Pragma("unroll")                                                      \
      for (int mj = 0; mj < 4; ++mj)                                         \
        acc[ci][mj] = __builtin_amdgcn_mfma_f32_16x16x32_bf16(               \
            wf[ci], sf[mj], acc[ci][mj], 0, 0, 0);                           \
    __builtin_amdgcn_s_setprio(0);                                           \
    __builtin_amdgcn_s_barrier();                                            \
  }

#define VMW(N) asm volatile("s_waitcnt vmcnt(" #N ")" ::: "memory")

  // prologue: batch0 of job0 -> buf0 (6 issues)
  {
    const int64_t mr0 = (int64_t)mtb * 128;
    stW(0, 0, 0); stW(0, 0, 1); stW(0, 0, 2); stW(0, 0, 3);
    stS(0, 0, 0, mr0); stS(0, 0, 1, mr0);
  }

  for (int i = 0; i < 7; ++i) {
    const int64_t mrow0  = (int64_t)(mtb + 56 * i) * 128;
    const bool    lastj  = (i == 6);
    const int64_t mrow0n = lastj ? mrow0 : (int64_t)(mtb + 56 * (i + 1)) * 128;

    // ---- tile 0 (buf0): issue b1->buf1 (ph0), b2->buf2 (ph1)
    if (i == 0) { VMW(0); } else { VMW(16); }   // steady: 16 stores younger than b0'
    __builtin_amdgcn_s_barrier();
    PHASE(0, 0,
          stW(1, 64, 0); stW(1, 64, 1); stW(1, 64, 2); stW(1, 64, 3);
          stS(1, 64, 0, mrow0); stS(1, 64, 1, mrow0));
    PHASE(0, 64,
          stW(2, 128, 0); stW(2, 128, 1); stW(2, 128, 2); stW(2, 128, 3);
          stS(2, 128, 0, mrow0); stS(2, 128, 1, mrow0));

    // ---- tile 1 (buf1): issue b3->buf0
    VMW(6);
    __builtin_amdgcn_s_barrier();
    PHASE(1, 0,  stW(0, 192, 0); stW(0, 192, 1); stS(0, 192, 0, mrow0));
    PHASE(1, 64, stW(0, 192, 2); stW(0, 192, 3); stS(0, 192, 1, mrow0));

    // ---- tile 2 (buf2): issue b4->buf1
    VMW(6);
    __builtin_amdgcn_s_barrier();
    PHASE(2, 0,  stW(1, 256, 0); stW(1, 256, 1); stS(1, 256, 0, mrow0));
    PHASE(2, 64, stW(1, 256, 2); stW(1, 256, 3); stS(1, 256, 1, mrow0));

    // ---- tile 3 (buf0): issue b5->buf2
    VMW(6);
    __builtin_amdgcn_s_barrier();
    PHASE(0, 0,  stW(2, 320, 0); stW(2, 320, 1); stS(2, 320, 0, mrow0));
    PHASE(0, 64, stW(2, 320, 2); stW(2, 320, 3); stS(2, 320, 1, mrow0));

    // ---- tile 4 (buf1): issue b6->buf0
    VMW(6);
    __builtin_amdgcn_s_barrier();
    PHASE(1, 0,  stW(0, 384, 0); stW(0, 384, 1); stS(0, 384, 0, mrow0));
    PHASE(1, 64, stW(0, 384, 2); stW(0, 384, 3); stS(0, 384, 1, mrow0));

    // ---- tile 5 (buf2): issue b7->buf1
    VMW(6);
    __builtin_amdgcn_s_barrier();
    PHASE(2, 0,  stW(1, 448, 0); stW(1, 448, 1); stS(1, 448, 0, mrow0));
    PHASE(2, 64, stW(1, 448, 2); stW(1, 448, 3); stS(1, 448, 1, mrow0));

    // ---- tile 6 (buf0): no issues (next target buf0 is in use here)
    VMW(6);
    __builtin_amdgcn_s_barrier();
    PHASE(0, 0, );
    PHASE(0, 64, );

    // ---- tile 7 (buf1): issue next job's b0'->buf0 (buf0 readers done)
    VMW(0);   // b7 was issued 2 tiles ago; near-free drain
    __builtin_amdgcn_s_barrier();
    if (!lastj) {
      PHASE(1, 0,  stW(0, 0, 0); stW(0, 0, 1); stW(0, 0, 2));
      PHASE(1, 64, stW(0, 0, 3); stS(0, 0, 0, mrow0n); stS(0, 0, 1, mrow0n));
    } else {
      PHASE(1, 0, );
      PHASE(1, 64, );
    }

    // ---- epilogue stores: exactly 16 dwordx4 per thread (counted in the
    // next tile0's vmcnt(16)). Order pinned after b0' issues.
    __builtin_amdgcn_sched_barrier(0);
    asm volatile("" ::: "memory");
#pragma unroll
    for (int ci = 0; ci < 4; ++ci) {
      const int  cq = c0 + wcb + ci * 16 + (lane >> 4) * 4;
      const bool ok = (cq < C_DIM);
#pragma unroll
      for (int mj = 0; mj < 4; ++mj) {
        const int64_t m = mrow0 + wmb + mj * 16 + lr;
        float4 o;
        o.x = acc[ci][mj][0] + bv[ci].x;
        o.y = acc[ci][mj][1] + bv[ci].y;
        o.z = acc[ci][mj][2] + bv[ci].z;
        o.w = acc[ci][mj][3] + bv[ci].w;
        float* p = ok ? (Y + m * C_DIM + cq) : (dump + (tid & 511) * 4);
        *(float4*)p = o;
        acc[ci][mj] = (f32x4){0.f, 0.f, 0.f, 0.f};
      }
    }
    asm volatile("" ::: "memory");
  }
#undef PHASE
#undef VMW
}

// ---------------------------------------------------------------------------
extern "C" void kernel_launch(void* const* d_in, const int* in_sizes, int n_in,
                              void* d_out, int out_size, void* d_ws, size_t ws_size,
                              hipStream_t stream) {
  const float* x = (const float*)d_in[0];
  const float* W = (const float*)d_in[1];
  const float* b = (const float*)d_in[2];
  float* Y = (float*)d_out;

  unsigned short* S  = (unsigned short*)d_ws;            // 50176*512 bf16 = 51.4 MB
  unsigned short* Wb = S + (size_t)M_ROWS * K_DIM;       // 1024*512 bf16  =  1.0 MB
  float* dump = (float*)(Wb + (size_t)1024 * 512);       // 8 KB spill target

  hipLaunchKernelGGL(wconv_kernel, dim3(512), dim3(256), 0, stream, W, Wb);
  hipLaunchKernelGGL(lif_kernel, dim3(2048), dim3(256), 0, stream, x, S);
  hipLaunchKernelGGL(gemm_kernel, dim3(224), dim3(512), 0, stream, S, Wb, b, Y, dump);
}

// Round 5
// 123.461 us; speedup vs baseline: 1.4531x; 1.4531x over previous
//
#include <hip/hip_runtime.h>
#include <hip/hip_bf16.h>
#include <stdint.h>

// ---------------------------------------------------------------------------
// Decoder_10110353014984: LIF multistep (T=4) + linear head
//   x: [4,64,196,512] f32, W: [1000,512] f32, b: [1000] f32
//   y: [4,64,196,1000] f32
// R5 = R4 with the nontemporal store typed as ext_vector f32x4 (compile fix).
//      Theory: all rounds pinned at ~2 TB/s effective write BW from 64B
//      scattered row-segments (partial-line RMW). Epilogue stages acc in LDS
//      and streams full 128B lines (one wave = one 1024B row run).
// ---------------------------------------------------------------------------

typedef __attribute__((ext_vector_type(8))) short bf16x8;
typedef __attribute__((ext_vector_type(4))) float f32x4;

#define AS1(p) ((const __attribute__((address_space(1))) void*)(p))
#define AS3(p) ((__attribute__((address_space(3))) void*)(p))

static constexpr int     T_STEPS = 4;
static constexpr int64_t ESP     = 6422528;   // B*N*D = 64*196*512
static constexpr int     K_DIM   = 512;
static constexpr int     C_DIM   = 1000;
static constexpr int64_t M_ROWS  = 50176;     // T*B*N

__device__ __forceinline__ unsigned short f2bf(float f) {
  unsigned int u = __float_as_uint(f);
  u += 0x7FFFu + ((u >> 16) & 1u);            // round-to-nearest-even
  return (unsigned short)(u >> 16);
}

// ---------------------------------------------------------------------------
// Kernel 1: LIF dynamics -> bf16 spikes. Bit-exact vs reference:
// v += (x - v) * 0.5f (exact *0.5), spike iff v >= 1.0f, hard reset.
// ---------------------------------------------------------------------------
__global__ void lif_kernel(const float* __restrict__ x,
                           unsigned short* __restrict__ S) {
  const int64_t stride = (int64_t)gridDim.x * blockDim.x;
  const int64_t nquads = ESP / 4;
  for (int64_t q = (int64_t)blockIdx.x * blockDim.x + threadIdx.x;
       q < nquads; q += stride) {
    const int64_t s0 = q << 2;
    float v[4] = {0.f, 0.f, 0.f, 0.f};
#pragma unroll
    for (int t = 0; t < T_STEPS; ++t) {
      const float4 xt = *(const float4*)(x + (int64_t)t * ESP + s0);
      const float xa[4] = {xt.x, xt.y, xt.z, xt.w};
      ushort4 sp;
      unsigned short* spp = &sp.x;
#pragma unroll
      for (int j = 0; j < 4; ++j) {
        v[j] = v[j] + (xa[j] - v[j]) * 0.5f;   // charge
        const bool fire = (v[j] >= 1.0f);
        spp[j] = fire ? (unsigned short)0x3F80 : (unsigned short)0; // bf16 1/0
        if (fire) v[j] = 0.0f;                 // hard reset
      }
      *(ushort4*)(S + (int64_t)t * ESP + s0) = sp;
    }
  }
}

// ---------------------------------------------------------------------------
// Kernel 2: W f32[1000,512] -> bf16[1024,512], rows 1000..1023 zeroed.
// ---------------------------------------------------------------------------
__global__ void wconv_kernel(const float* __restrict__ W,
                             unsigned short* __restrict__ Wb) {
  const int idx = blockIdx.x * blockDim.x + threadIdx.x;  // 0..131071
  const int64_t base = (int64_t)idx * 4;
  const int row = (int)(base >> 9);
  ushort4 o;
  if (row < C_DIM) {
    const float4 wv = *(const float4*)(W + base);
    o.x = f2bf(wv.x); o.y = f2bf(wv.y); o.z = f2bf(wv.z); o.w = f2bf(wv.w);
  } else {
    o.x = o.y = o.z = o.w = 0;
  }
  *(ushort4*)(Wb + base) = o;
}

// ---------------------------------------------------------------------------
// Kernel 3: GEMM  Y[m,c] = sum_d S[m,d] * Wb[c,d] + b[c]
// 256x256 tile, BK=64, 512 threads (8 waves, 2Mx4N), dbuf LDS 128KB.
// Main loop identical to R2 (proven). Epilogue: 4 slices of 64 rows;
// owning waves scatter acc+bias into a swizzled 64KB LDS slice; then all
// 8 waves stream it out, one wave per row: 64 lanes x float4 = contiguous
// 1024B of full 128B lines, nontemporal.
// ---------------------------------------------------------------------------
__global__ __launch_bounds__(512) void gemm_kernel(
    const unsigned short* __restrict__ S,
    const unsigned short* __restrict__ Wb,
    const float* __restrict__ bias,
    float* __restrict__ Y) {
  __shared__ __attribute__((aligned(16))) unsigned short As[2][256 * 64];
  __shared__ __attribute__((aligned(16))) unsigned short Bs[2][256 * 64];

  const int tid  = threadIdx.x;
  const int lane = tid & 63;
  const int wid  = tid >> 6;      // 0..7
  const int wm   = wid >> 2;      // 0..1  (M half: 128 rows)
  const int wn   = wid & 3;       // 0..3  (N quarter: 64 cols)

  // XCD-aware swizzle: 784 blocks, 784 % 8 == 0 -> bijective; swz>>2 = mtile
  // so the 4 N-tiles of an M-tile are adjacent on one XCD (S L2-shared).
  const int bid   = blockIdx.x;
  const int swz   = (bid & 7) * 98 + (bid >> 3);
  const int mtile = swz >> 2;
  const int ntile = swz & 3;
  const int64_t row0 = (int64_t)mtile * 256;
  const int     c0   = ntile * 256;

  // staging: LDS dest is wave-uniform base (+ lane*16 by HW); swizzle on the
  // GLOBAL source column: ((lane&7) ^ (lane>>3)) << 4.
  const int srow = lane >> 3;                 // 0..7
  const int skb  = ((lane & 7) ^ srow) << 4;

  const char* Sg = (const char*)S;
  const char* Wg = (const char*)Wb;

  f32x4 acc[8][4] = {};

  auto stageA = [&](int buf, int k0, int i) {
    const int64_t gr = row0 + i * 64 + wid * 8 + srow;
    __builtin_amdgcn_global_load_lds(
        AS1(Sg + (gr * K_DIM + k0) * 2 + skb),
        AS3((char*)&As[buf][0] + (i * 64 + wid * 8) * 128), 16, 0, 0);
  };
  auto stageB = [&](int buf, int k0, int i) {
    const int64_t gr = (int64_t)c0 + i * 64 + wid * 8 + srow;
    __builtin_amdgcn_global_load_lds(
        AS1(Wg + (gr * K_DIM + k0) * 2 + skb),
        AS3((char*)&Bs[buf][0] + (i * 64 + wid * 8) * 128), 16, 0, 0);
  };

  // prologue: stage K-tile 0 into buf 0
#pragma unroll
  for (int i = 0; i < 4; ++i) stageA(0, 0, i);
#pragma unroll
  for (int i = 0; i < 4; ++i) stageB(0, 0, i);
  __syncthreads();

  const int lr = lane & 15;
  const int lk = (lane >> 4) * 16;
  bf16x8 bfr[4];

  int cur = 0;
  for (int t = 0; t < 8; ++t) {            // 8 K-tiles of 64
    const int  k0n = (t + 1) * 64;
    const bool pf  = (t < 7);
    const int  nxt = cur ^ 1;
    const char* Ab = (const char*)&As[cur][0];
    const char* Bb = (const char*)&Bs[cur][0];

#pragma unroll
    for (int half = 0; half < 2; ++half) { // kk slice of BK=64
      const int kb = half * 64 + lk;
      bf16x8 afr[4];

      // ---- phase (half,0): frags mi 0-3 + B frags ----
#pragma unroll
      for (int mi = 0; mi < 4; ++mi) {
        const int r = wm * 128 + mi * 16 + lr;
        afr[mi] = *(const bf16x8*)(Ab + r * 128 + (kb ^ ((r & 7) << 4)));
      }
#pragma unroll
      for (int nj = 0; nj < 4; ++nj) {
        const int r = wn * 64 + nj * 16 + lr;
        bfr[nj] = *(const bf16x8*)(Bb + r * 128 + (kb ^ ((r & 7) << 4)));
      }
      if (pf) {
        if (half == 0) { stageA(nxt, k0n, 0); stageA(nxt, k0n, 1); }
        else           { stageB(nxt, k0n, 0); stageB(nxt, k0n, 1); }
      }
      __builtin_amdgcn_s_barrier();
      asm volatile("s_waitcnt lgkmcnt(0)" ::: "memory");
      __builtin_amdgcn_sched_barrier(0);
      __builtin_amdgcn_s_setprio(1);
#pragma unroll
      for (int mi = 0; mi < 4; ++mi)
#pragma unroll
        for (int nj = 0; nj < 4; ++nj)
          acc[mi][nj] = __builtin_amdgcn_mfma_f32_16x16x32_bf16(
              afr[mi], bfr[nj], acc[mi][nj], 0, 0, 0);
      __builtin_amdgcn_s_setprio(0);
      __builtin_amdgcn_s_barrier();

      // ---- phase (half,1): frags mi 4-7 (B reused) ----
#pragma unroll
      for (int mi = 0; mi < 4; ++mi) {
        const int r = wm * 128 + (mi + 4) * 16 + lr;
        afr[mi] = *(const bf16x8*)(Ab + r * 128 + (kb ^ ((r & 7) << 4)));
      }
      if (pf) {
        if (half == 0) { stageA(nxt, k0n, 2); stageA(nxt, k0n, 3); }
        else           { stageB(nxt, k0n, 2); stageB(nxt, k0n, 3); }
      }
      __builtin_amdgcn_s_barrier();
      asm volatile("s_waitcnt lgkmcnt(0)" ::: "memory");
      __builtin_amdgcn_sched_barrier(0);
      __builtin_amdgcn_s_setprio(1);
#pragma unroll
      for (int mi = 0; mi < 4; ++mi)
#pragma unroll
        for (int nj = 0; nj < 4; ++nj)
          acc[mi + 4][nj] = __builtin_amdgcn_mfma_f32_16x16x32_bf16(
              afr[mi], bfr[nj], acc[mi + 4][nj], 0, 0, 0);
      __builtin_amdgcn_s_setprio(0);
      __builtin_amdgcn_s_barrier();
    }
    __syncthreads();
    cur = nxt;
  }

  // ---- epilogue: LDS-staged full-line streaming stores ----
  // acc[mi][nj][r] belongs to Y[row0 + wm*128 + mi*16 + (lane>>4)*4 + r]
  //                            [c0 + wn*64 + nj*16 + lr]
  float bvn[4];
#pragma unroll
  for (int nj = 0; nj < 4; ++nj) {
    const int c = c0 + wn * 64 + nj * 16 + lr;
    bvn[nj] = (c < C_DIM) ? bias[c] : 0.f;
  }

  char* obuf = (char*)&As[0][0];                 // 64KB, staging is dead
  const int cw4 = (C_DIM - c0 < 256 ? C_DIM - c0 : 256) * 4; // panel bytes/row
  const int rw  = tid >> 6;                      // row-in-pass (wave id)
  const int cb  = (tid & 63) * 16;               // byte offset within row

#pragma unroll
  for (int slice = 0; slice < 4; ++slice) {
    __syncthreads();                             // LDS free for this slice
    if (wm == (slice >> 1)) {
      const int mi0 = (slice & 1) * 4;
#pragma unroll
      for (int mi2 = 0; mi2 < 4; ++mi2) {
#pragma unroll
        for (int nj = 0; nj < 4; ++nj) {
          const int cl = (wn * 64 + nj * 16 + lr) * 4;
#pragma unroll
          for (int r = 0; r < 4; ++r) {
            const int rl = mi2 * 16 + (lane >> 4) * 4 + r;   // 0..63
            *(float*)(obuf + ((rl * 1024 + cl) ^ ((rl & 7) << 4))) =
                acc[mi0 + mi2][nj][r] + bvn[nj];
          }
        }
      }
    }
    __syncthreads();                             // slice fully written
    // stream: 8 passes x 8 rows; one wave owns one row (1024B contiguous)
#pragma unroll
    for (int pass = 0; pass < 8; ++pass) {
      const int rl = pass * 8 + rw;
      const f32x4 v =
          *(const f32x4*)(obuf + ((rl * 1024 + cb) ^ ((rl & 7) << 4)));
      if (cb < cw4) {
        const int64_t m = row0 + slice * 64 + rl;
        f32x4* dst = (f32x4*)((char*)(Y + m * (int64_t)C_DIM + c0) + cb);
        __builtin_nontemporal_store(v, dst);
      }
    }
  }
}

// ---------------------------------------------------------------------------
extern "C" void kernel_launch(void* const* d_in, const int* in_sizes, int n_in,
                              void* d_out, int out_size, void* d_ws, size_t ws_size,
                              hipStream_t stream) {
  const float* x = (const float*)d_in[0];
  const float* W = (const float*)d_in[1];
  const float* b = (const float*)d_in[2];
  float* Y = (float*)d_out;

  unsigned short* S  = (unsigned short*)d_ws;            // 50176*512 bf16 = 51.4 MB
  unsigned short* Wb = S + (size_t)M_ROWS * K_DIM;       // 1024*512 bf16  =  1.0 MB

  hipLaunchKernelGGL(wconv_kernel, dim3(512), dim3(256), 0, stream, W, Wb);
  hipLaunchKernelGGL(lif_kernel, dim3(2048), dim3(256), 0, stream, x, S);
  hipLaunchKernelGGL(gemm_kernel, dim3(784), dim3(512), 0, stream, S, Wb, b, Y);
}